// Round 2
// baseline (1231.277 us; speedup 1.0000x reference)
//
#include <hip/hip_runtime.h>

#define NDET 600
#define IMG_HW (384 * 384)          // 147456 floats per mask row
#define NF4 (IMG_HW / 4)            // 36864 float4 per mask row
#define SLOTS 10                    // ceil(600/64) sorted positions per lane
#define SCORE_THRESH 0.001f

// ---------------------------------------------------------------------------
// Kernel 1: class-shift + stable sort + sequential gaussian soft-NMS.
// ONE WAVEFRONT (64 lanes). Lane l owns sorted positions p = l + 64k,
// k = 0..9, all state in statically-indexed registers. No barriers in the
// 600-step scan: broadcasts are __shfl, updates are wave-lockstep in-order.
// ---------------------------------------------------------------------------
__global__ __launch_bounds__(64) void nms_kernel(
    const float4* __restrict__ boxes4, const float* __restrict__ scores,
    const int* __restrict__ labels, float* __restrict__ out_keep,
    float* __restrict__ out_score, int* __restrict__ keep_ws)
{
    const int l = threadIdx.x;

    __shared__ float s_sc[NDET];
    __shared__ float wx1[NDET], wy1[NDET], wx2[NDET], wy2[NDET];
    __shared__ float war[NDET], wsc[NDET];
    __shared__ int   worig[NDET];

    for (int t = l; t < NDET; t += 64) s_sc[t] = scores[t];

    // ---- max over all box coords (reference: boxes.max() + 1) ----
    float m = -1e30f;
    for (int t = l; t < NDET; t += 64) {
        const float4 b = boxes4[t];
        m = fmaxf(fmaxf(m, fmaxf(b.x, b.y)), fmaxf(b.z, b.w));
    }
    #pragma unroll
    for (int off = 32; off; off >>= 1) m = fmaxf(m, __shfl_xor(m, off));
    const float max_coord = m + 1.0f;

    __syncthreads();   // s_sc visible (single wave: cheap)

    // ---- shift owned originals (t = l + 64k); stable descending rank ----
    float ox1[SLOTS], oy1[SLOTS], ox2[SLOTS], oy2[SLOTS], osc[SLOTS];
    int   rank[SLOTS];
    #pragma unroll
    for (int k = 0; k < SLOTS; ++k) {
        const int t = l + 64 * k;
        if (t < NDET) {
            const float4 b = boxes4[t];
            const float shf = (float)labels[t] * max_coord;
            ox1[k] = b.x + shf; oy1[k] = b.y + shf;
            ox2[k] = b.z + shf; oy2[k] = b.w + shf;
            osc[k] = s_sc[t];
            rank[k] = 0;
        }
    }
    for (int j = 0; j < NDET; ++j) {
        const float sj = s_sc[j];
        #pragma unroll
        for (int k = 0; k < SLOTS; ++k) {
            const int t = l + 64 * k;
            if (t < NDET)
                rank[k] += (sj > osc[k]) || (sj == osc[k] && j < t);
        }
    }
    // scatter to sorted LDS arrays
    #pragma unroll
    for (int k = 0; k < SLOTS; ++k) {
        const int t = l + 64 * k;
        if (t < NDET) {
            const int r = rank[k];
            wx1[r] = ox1[k]; wy1[r] = oy1[k];
            wx2[r] = ox2[k]; wy2[r] = oy2[k];
            war[r] = (ox2[k] - ox1[k]) * (oy2[k] - oy1[k]);  // area of shifted, as ref
            wsc[r] = osc[k];
            worig[r] = t;
        }
    }
    __syncthreads();

    // ---- gather sorted slots into registers (conflict-free: stride-1 lanes)
    float rx1[SLOTS], ry1[SLOTS], rx2[SLOTS], ry2[SLOTS], ra[SLOTS], rs[SLOTS];
    int   rorig[SLOTS];
    int   actmask = 0;
    #pragma unroll
    for (int k = 0; k < SLOTS; ++k) {
        const int p = l + 64 * k;
        if (p < NDET) {
            rx1[k] = wx1[p]; ry1[k] = wy1[p];
            rx2[k] = wx2[p]; ry2[k] = wy2[p];
            ra[k]  = war[p]; rs[k]  = wsc[p];
            rorig[k] = worig[p];
            actmask |= 1 << k;
        }
    }

    // ---- sequential scan, barrier-free: i = s*64 + li ----
    #pragma unroll
    for (int s = 0; s < SLOTS; ++s) {
        const int base = s * 64;
        const int nIn = (NDET - base) < 64 ? (NDET - base) : 64;
        for (int li = 0; li < nIn; ++li) {
            const int am = __shfl(actmask, li);
            if (!((am >> s) & 1)) continue;            // i inactive: uniform skip
            const float ix1 = __shfl(rx1[s], li);
            const float iy1 = __shfl(ry1[s], li);
            const float ix2 = __shfl(rx2[s], li);
            const float iy2 = __shfl(ry2[s], li);
            const float ia  = __shfl(ra[s],  li);
            #pragma unroll
            for (int k = s; k < SLOTS; ++k) {          // only p > i can be hit
                const bool applies = (k > s) || (l > li);
                if (applies && ((actmask >> k) & 1)) {
                    const float w = fminf(rx2[k], ix2) - fmaxf(rx1[k], ix1);
                    const float h = fminf(ry2[k], iy2) - fmaxf(ry1[k], iy1);
                    if (w > 0.f && h > 0.f) {          // inter==0 => decay==1 exactly
                        const float inter = w * h;
                        const float iou = inter / (ra[k] + ia - inter);
                        rs[k] *= expf(-(iou * iou) / 0.5f);   // SIGMA = 0.5
                        if (!(rs[k] > SCORE_THRESH)) actmask &= ~(1 << k);
                    }
                }
            }
        }
    }

    // ---- scatter outputs to original order ----
    #pragma unroll
    for (int k = 0; k < SLOTS; ++k) {
        const int p = l + 64 * k;
        if (p < NDET) {
            const int a = (actmask >> k) & 1;
            out_keep[rorig[k]]  = a ? 1.0f : 0.0f;
            out_score[rorig[k]] = a ? rs[k] : 0.0f;
            keep_ws[rorig[k]]   = a;
        }
    }
}

// ---------------------------------------------------------------------------
// Kernel 2: per-row match list (same class, unshifted IoU > 0.5), cnt, use_avg
// ---------------------------------------------------------------------------
__global__ __launch_bounds__(256) void match_kernel(
    const float* __restrict__ boxes, const int* __restrict__ labels,
    const int* __restrict__ keep_ws, int* __restrict__ cnt_ws,
    int* __restrict__ ua_ws, int* __restrict__ list_ws)
{
    const int i = blockIdx.x;
    const int tid = threadIdx.x;
    __shared__ int mflag[NDET];

    const float ix1 = boxes[4 * i + 0], iy1 = boxes[4 * i + 1];
    const float ix2 = boxes[4 * i + 2], iy2 = boxes[4 * i + 3];
    const float ia = (ix2 - ix1) * (iy2 - iy1);
    const int li = labels[i];

    for (int j = tid; j < NDET; j += 256) {
        const float jx1 = boxes[4 * j + 0], jy1 = boxes[4 * j + 1];
        const float jx2 = boxes[4 * j + 2], jy2 = boxes[4 * j + 3];
        const float ja = (jx2 - jx1) * (jy2 - jy1);
        float w = fminf(ix2, jx2) - fmaxf(ix1, jx1);
        float h = fminf(iy2, jy2) - fmaxf(iy1, jy1);
        w = fmaxf(w, 0.f); h = fmaxf(h, 0.f);
        const float inter = w * h;
        const float iou = inter / (ia + ja - inter);
        mflag[j] = (labels[j] == li) && (iou > 0.5f);
    }
    __syncthreads();

    if (tid == 0) {
        int c = 0;
        for (int j = 0; j < NDET; j++)
            if (mflag[j]) list_ws[i * NDET + (c++)] = j;
        cnt_ws[i] = c;
        ua_ws[i] = (keep_ws[i] && c > 1) ? 1 : 0;
    }
}

// ---------------------------------------------------------------------------
// Kernel 3: mask output. Copy row unless use_avg; else gather+avg matched rows.
// grid = (NF4/256, NDET), block = 256, one float4 per thread.
// ---------------------------------------------------------------------------
__global__ __launch_bounds__(256) void mask_kernel(
    const float4* __restrict__ masks, const int* __restrict__ cnt_ws,
    const int* __restrict__ ua_ws, const int* __restrict__ list_ws,
    float4* __restrict__ out)
{
    const int row = blockIdx.y;
    const int c4 = blockIdx.x * 256 + threadIdx.x;   // < NF4 by construction

    float4 r;
    if (!ua_ws[row]) {
        r = masks[(size_t)row * NF4 + c4];
    } else {
        const int c = cnt_ws[row];
        float4 acc = make_float4(0.f, 0.f, 0.f, 0.f);
        for (int k = 0; k < c; k++) {
            const int j = list_ws[row * NDET + k];
            const float4 v = masks[(size_t)j * NF4 + c4];
            acc.x += v.x; acc.y += v.y; acc.z += v.z; acc.w += v.w;
        }
        const float fc = (float)c;
        r.x = acc.x / fc; r.y = acc.y / fc; r.z = acc.z / fc; r.w = acc.w / fc;
    }
    out[(size_t)row * NF4 + c4] = r;
}

// ---------------------------------------------------------------------------
extern "C" void kernel_launch(void* const* d_in, const int* in_sizes, int n_in,
                              void* d_out, int out_size, void* d_ws, size_t ws_size,
                              hipStream_t stream) {
    const float* boxes  = (const float*)d_in[0];   // [600,4]
    const float* scores = (const float*)d_in[1];   // [600]
    const float* masks  = (const float*)d_in[2];   // [600,1,384,384]
    const int*   labels = (const int*)d_in[3];     // [600]

    float* out = (float*)d_out;                    // [keep(600) | scores(600) | masks(600*147456)]

    int* keep_ws = (int*)d_ws;                     // [600]
    int* cnt_ws  = keep_ws + NDET;                 // [600]
    int* ua_ws   = cnt_ws + NDET;                  // [600]
    int* list_ws = ua_ws + NDET;                   // [600*600]

    nms_kernel<<<1, 64, 0, stream>>>((const float4*)boxes, scores, labels,
                                     out, out + NDET, keep_ws);
    match_kernel<<<NDET, 256, 0, stream>>>(boxes, labels, keep_ws,
                                           cnt_ws, ua_ws, list_ws);
    mask_kernel<<<dim3(NF4 / 256, NDET), 256, 0, stream>>>(
        (const float4*)masks, cnt_ws, ua_ws, list_ws,
        (float4*)(out + 2 * NDET));
}